// Round 7
// baseline (488.853 us; speedup 1.0000x reference)
//
#include <hip/hip_runtime.h>

// N=8, L=2048, E=1024, V=512. Only l=L-1 feeds logits.
// R7: ONE kernel, 512 blocks x 512 threads (2/CU co-resident), 4 stages with
// 3 device-scope grid barriers. Tests whether the ~20us fixed cost is
// inter-dispatch overhead (then this drops to ~20us) or per-replay floor.
// No nontemporal loads (tokens are L3-resident across replays - R6 lesson).
#define NB 8
#define LS 2048
#define ED 1024
#define VD 512
#define CM 32           // m-rows per flash chunk
#define CH (LS / CM)    // 64 chunks
#define GRID 512
typedef unsigned long long u64;

__device__ inline float wave_reduce_sum(float v) {
    #pragma unroll
    for (int off = 32; off > 0; off >>= 1)
        v += __shfl_down(v, off, 64);
    return v;
}

// Device-scope grid barrier. All GRID blocks must be co-resident (they are:
// 2 blocks/CU of 8 waves, launch_bounds caps VGPR<=128, LDS ~11KB).
__device__ inline void grid_barrier(unsigned* ctr) {
    __threadfence();              // release: my stores -> device coherence point
    __syncthreads();
    if (threadIdx.x == 0) {
        atomicAdd(ctr, 1u);       // device scope by default
        while (__hip_atomic_load(ctr, __ATOMIC_ACQUIRE, __HIP_MEMORY_SCOPE_AGENT) < GRID)
            __builtin_amdgcn_s_sleep(1);
    }
    __syncthreads();
    __threadfence();              // acquire: invalidate stale cached lines
}

__global__ __launch_bounds__(512, 4) void k_all(const int* __restrict__ tokens,
                                                const float* __restrict__ Wa_w,
                                                const float* __restrict__ Wa_b,
                                                const float* __restrict__ Wb_w,
                                                const float* __restrict__ Wb_b,
                                                float* __restrict__ q_row,
                                                float* __restrict__ pa,
                                                float* __restrict__ mu_g,
                                                float* __restrict__ z_g,
                                                float* __restrict__ a_row,
                                                unsigned* __restrict__ ctr,
                                                float* __restrict__ out) {
    int b = blockIdx.x;
    int t = threadIdx.x;
    int wave = t >> 6, lane = t & 63;

    __shared__ u64   pk[CM][16];   // 4 KB
    __shared__ float q_lds[ED];    // 4 KB
    __shared__ float s_lds[CM];
    __shared__ float p_lds[CM];
    __shared__ float coef[CH];
    __shared__ float part[32][16]; // 2 KB

    // ================= stage A: q_row =================
    // 4096 waves; wave gw -> n = gw>>9, f = (gw&511)*2 .. +1 (same token row).
    {
        int gw = b * 8 + wave;
        int n  = gw >> 9;
        int f  = (gw & 511) << 1;
        const int*   xrow = tokens + ((size_t)n * LS + (LS - 1)) * ED;
        const float* w0   = Wa_w + (size_t)f * ED;
        const float* w1   = w0 + ED;
        float a0 = 0.f, a1 = 0.f;
        #pragma unroll
        for (int k = 0; k < ED; k += 256) {
            int idx = k + lane * 4;
            int4   tv = *reinterpret_cast<const int4*>(xrow + idx);
            float4 f0 = *reinterpret_cast<const float4*>(w0 + idx);
            float4 f1 = *reinterpret_cast<const float4*>(w1 + idx);
            float tx = (float)tv.x, ty = (float)tv.y, tz = (float)tv.z, tw = (float)tv.w;
            a0 += tx * f0.x + ty * f0.y + tz * f0.z + tw * f0.w;
            a1 += tx * f1.x + ty * f1.y + tz * f1.z + tw * f1.w;
        }
        a0 = wave_reduce_sum(a0);
        a1 = wave_reduce_sum(a1);
        if (lane == 0) {
            q_row[n * ED + f]     = a0 + Wa_b[f];
            q_row[n * ED + f + 1] = a1 + Wa_b[f + 1];
        }
    }
    grid_barrier(ctr);

    // ================= stage B: flash (scores + chunk softmax + bit-sum) =====
    {
        int n = b >> 6;            // /CH
        int c = b & (CH - 1);
        *reinterpret_cast<float2*>(&q_lds[t * 2]) =
            *reinterpret_cast<const float2*>(&q_row[n * ED + t * 2]);
        __syncthreads();

        // phase 1: scores + bit-pack (8 waves x 4 rows)
        #pragma unroll
        for (int i = 0; i < 4; ++i) {
            int m = wave + 8 * i;
            const int* row = tokens + ((size_t)(n * LS + c * CM + m)) * ED;
            float acc = 0.f;
            #pragma unroll
            for (int k = 0; k < ED; k += 256) {
                int idx = k + lane * 4;
                int4   tv = *reinterpret_cast<const int4*>(row + idx);
                float4 qv = *reinterpret_cast<const float4*>(&q_lds[idx]);
                u64 b0 = __ballot(tv.x != 0);
                u64 b1 = __ballot(tv.y != 0);
                u64 b2 = __ballot(tv.z != 0);
                u64 b3 = __ballot(tv.w != 0);
                if (lane == 0) {
                    int wb = (k >> 8) * 4;  // e=k+4*lane+j -> word (e>>8)*4+(e&3), bit (e>>2)&63
                    pk[m][wb + 0] = b0; pk[m][wb + 1] = b1;
                    pk[m][wb + 2] = b2; pk[m][wb + 3] = b3;
                }
                acc += (float)tv.x * qv.x + (float)tv.y * qv.y
                     + (float)tv.z * qv.z + (float)tv.w * qv.w;
            }
            acc = wave_reduce_sum(acc);
            if (lane == 0) s_lds[m] = acc;
        }
        __syncthreads();

        // phase 2: chunk softmax stats
        if (wave == 0) {
            float s = (lane < CM) ? s_lds[lane] : -3.0e38f;
            float mx = s;
            #pragma unroll
            for (int off = 16; off > 0; off >>= 1) mx = fmaxf(mx, __shfl_xor(mx, off, 64));
            float p = (lane < CM) ? expf(s - mx) : 0.f;
            float z = p;
            #pragma unroll
            for (int off = 16; off > 0; off >>= 1) z += __shfl_xor(z, off, 64);
            if (lane < CM) p_lds[lane] = p;
            if (lane == 0) { mu_g[b] = mx; z_g[b] = z; }
        }
        __syncthreads();

        // phase 3: weighted bit-sum; e0 = t, e1 = t + 512
        int w0  = ((t >> 8) << 2) | (t & 3);
        int bit = (t >> 2) & 63;
        float a0 = 0.f, a1 = 0.f;
        #pragma unroll 8
        for (int m = 0; m < CM; ++m) {
            float p  = p_lds[m];
            u64   lo = pk[m][w0];
            u64   hi = pk[m][w0 + 8];
            a0 += ((lo >> bit) & 1ull) ? p : 0.f;
            a1 += ((hi >> bit) & 1ull) ? p : 0.f;
        }
        float* par = pa + (size_t)b * ED;
        par[t]       = a0;
        par[t + 512] = a1;
    }
    grid_barrier(ctr + 1);

    // ================= stage C1: combine pa -> a_row =================
    // block b: n = b>>6, e-tile = (b&63)*16. coef[c] = exp(mu_c-mu)/Z.
    {
        int n  = b >> 6;
        int et = (b & 63) << 4;
        if (wave == 0) {
            float m_c = mu_g[n * CH + lane];
            float mx = m_c;
            #pragma unroll
            for (int off = 32; off > 0; off >>= 1) mx = fmaxf(mx, __shfl_xor(mx, off, 64));
            float cf = expf(m_c - mx);
            float zc = z_g[n * CH + lane] * cf;
            float Z = zc;
            #pragma unroll
            for (int off = 32; off > 0; off >>= 1) Z += __shfl_xor(Z, off, 64);
            coef[lane] = cf / Z;
        }
        __syncthreads();
        // thread t: e_local = t&15, cg = t>>4 (32 groups of 2 chunks)
        int e_local = t & 15;
        int cg      = t >> 4;
        int e       = et + e_local;
        float s = coef[cg * 2]     * pa[((size_t)(n * CH + cg * 2))     * ED + e]
                + coef[cg * 2 + 1] * pa[((size_t)(n * CH + cg * 2 + 1)) * ED + e];
        part[cg][e_local] = s;
        __syncthreads();
        if (t < 16) {
            float acc = 0.f;
            #pragma unroll
            for (int j = 0; j < 32; ++j) acc += part[j][t];
            a_row[n * ED + et + t] = acc;
        }
    }
    grid_barrier(ctr + 2);

    // ================= stage C2: output GEMV =================
    // block b: n = b>>6, v = (b&63)*8 + wave (one v per wave).
    {
        int n = b >> 6;
        int v = ((b & 63) << 3) + wave;
        const float* wr = Wb_w + (size_t)v * ED;
        const float* ar = a_row + n * ED;
        float d = 0.f;
        #pragma unroll
        for (int k = 0; k < ED; k += 256) {
            int idx = k + lane * 4;
            float4 wv = *reinterpret_cast<const float4*>(wr + idx);
            float4 av = *reinterpret_cast<const float4*>(ar + idx);
            d += av.x * wv.x + av.y * wv.y + av.z * wv.z + av.w * wv.w;
        }
        d = wave_reduce_sum(d);
        if (lane == 0) out[n * VD + v] = d + Wb_b[v];
    }
}

extern "C" void kernel_launch(void* const* d_in, const int* in_sizes, int n_in,
                              void* d_out, int out_size, void* d_ws, size_t ws_size,
                              hipStream_t stream) {
    const int*   tokens = (const int*)  d_in[0];
    const float* Wa_w   = (const float*)d_in[1];
    const float* Wa_b   = (const float*)d_in[2];
    const float* Wb_w   = (const float*)d_in[3];
    const float* Wb_b   = (const float*)d_in[4];
    float* out = (float*)d_out;

    unsigned* ctr = (unsigned*)d_ws;                    // 3 barrier counters
    float* fws    = (float*)((char*)d_ws + 256);
    float* q_row  = fws;                                // 8192
    float* pa     = q_row + NB * ED;                    // 8*64*1024 = 524288
    float* mu_g   = pa + (size_t)NB * CH * ED;          // 512
    float* z_g    = mu_g + NB * CH;                     // 512
    float* a_row  = z_g + NB * CH;                      // 8192

    // zero the barrier counters (captured as a graph node -> re-zeroed each replay)
    hipMemsetAsync(d_ws, 0, 256, stream);
    k_all<<<dim3(GRID), dim3(512), 0, stream>>>(tokens, Wa_w, Wa_b, Wb_w, Wb_b,
                                                q_row, pa, mu_g, z_g, a_row, ctr, out);
}

// Round 8
// 32.918 us; speedup vs baseline: 14.8507x; 14.8507x over previous
//
#include <hip/hip_runtime.h>

// N=8, L=2048, E=1024, V=512. Only l=L-1 feeds logits.
// R8: tokens (64 MB) are streamed ONCE by a pure pack kernel (ballot -> 2 MB
// of bits); scores/softmax/weighted-sum all run on the packed bits (L2-hot).
// K1 = pack + qrow (role-split, independent). K2 = flash-from-bits. K3 = out.
#define NB 8
#define LS 2048
#define ED 1024
#define VD 512
#define CM 32           // m-rows per flash block
#define CH (LS / CM)    // 64 chunks
typedef unsigned long long u64;

__device__ inline float wave_reduce_sum(float v) {
    #pragma unroll
    for (int off = 32; off > 0; off >>= 1)
        v += __shfl_down(v, off, 64);
    return v;
}

// K1 role-split:
//  blocks 0..1023   : pack role. wave packs 4 rows; per row 4 k-iters of
//                     {int4 load, 4 ballots, lane<4 writes 4 u64}.
//                     bit map: e = k + 4*lane + j -> word ((e>>8)<<2)|(e&3), bit lane.
//  blocks 1024..3071: qrow role (wave per (n,f)): q = Wa_b[f] + x_last . Wa_w[f].
__global__ __launch_bounds__(256) void k_pack_qrow(const int* __restrict__ tokens,
                                                   const float* __restrict__ Wa_w,
                                                   const float* __restrict__ Wa_b,
                                                   float* __restrict__ q_row,
                                                   u64* __restrict__ pk_g) {
    int b = blockIdx.x, t = threadIdx.x;
    int wave = t >> 6, lane = t & 63;
    if (b < 1024) {
        #pragma unroll
        for (int i = 0; i < 4; ++i) {
            int row = b * 16 + wave * 4 + i;        // row = n*LS + m, 0..16383
            const int* xr = tokens + (size_t)row * ED;
            u64* pkr = pk_g + (size_t)row * 16;
            #pragma unroll
            for (int k = 0; k < ED; k += 256) {
                int idx = k + lane * 4;
                int4 tv = *reinterpret_cast<const int4*>(xr + idx);
                u64 b0 = __ballot(tv.x != 0);
                u64 b1 = __ballot(tv.y != 0);
                u64 b2 = __ballot(tv.z != 0);
                u64 b3 = __ballot(tv.w != 0);
                u64 bb = b0;
                bb = (lane == 1) ? b1 : bb;
                bb = (lane == 2) ? b2 : bb;
                bb = (lane == 3) ? b3 : bb;
                if (lane < 4) pkr[((k >> 8) << 2) + lane] = bb;
            }
        }
    } else {
        int wid = (b - 1024) * 4 + wave;            // (n,f): wid = n*1024 + f
        int n = wid >> 10, f = wid & (ED - 1);
        const int*   xrow = tokens + ((size_t)n * LS + (LS - 1)) * ED;
        const float* wrow = Wa_w + (size_t)f * ED;
        float acc = 0.f;
        #pragma unroll
        for (int k = 0; k < ED; k += 256) {
            int idx = k + lane * 4;
            int4   tv = *reinterpret_cast<const int4*>(xrow + idx);
            float4 w  = *reinterpret_cast<const float4*>(wrow + idx);
            acc += (float)tv.x * w.x + (float)tv.y * w.y
                 + (float)tv.z * w.z + (float)tv.w * w.w;
        }
        acc = wave_reduce_sum(acc);
        if (lane == 0) q_row[wid] = acc + Wa_b[f];
    }
}

// K2: flash from bits. Block (512 thr, 8 waves) per (n, chunk of 32 m).
// Stage: pk rows (4 KB, coalesced) + q permuted so phase-1 reads are
// conflict-free: q_perm[w*64 + lane] = q[e], e = (w>>2)*256 + (w&3) + 4*lane.
// Phase 1: score[m] = sum_w sum_lane bit(w,lane) * q_perm[w*64+lane].
// Phase 2: chunk softmax stats. Phase 3: weighted bit-sum (same as R4).
__global__ __launch_bounds__(512) void k_flash(const float* __restrict__ q_row,
                                               const u64* __restrict__ pk_g,
                                               float* __restrict__ pa,
                                               float* __restrict__ mu_g,
                                               float* __restrict__ z_g) {
    int n = blockIdx.x >> 6;      // /CH
    int c = blockIdx.x & (CH - 1);
    int t = threadIdx.x;
    int wave = t >> 6, lane = t & 63;

    __shared__ u64   pk[CM * 16];   // 4 KB
    __shared__ float q_perm[ED];    // 4 KB
    __shared__ float s_lds[CM];
    __shared__ float p_lds[CM];

    pk[t] = pk_g[((size_t)(n * LS + c * CM)) * 16 + t];
    {
        float2 qq = *reinterpret_cast<const float2*>(&q_row[n * ED + t * 2]);
        int e0 = t * 2, e1 = e0 + 1;
        q_perm[((((e0 >> 8) << 2) | (e0 & 3)) << 6) | ((e0 >> 2) & 63)] = qq.x;
        q_perm[((((e1 >> 8) << 2) | (e1 & 3)) << 6) | ((e1 >> 2) & 63)] = qq.y;
    }
    __syncthreads();

    // ---- phase 1: masked-add scores (8 waves x 4 rows) ----
    #pragma unroll
    for (int i = 0; i < 4; ++i) {
        int m = wave + 8 * i;
        float acc = 0.f;
        #pragma unroll
        for (int w = 0; w < 16; ++w) {
            u64   word = pk[m * 16 + w];            // broadcast read
            float qv   = q_perm[(w << 6) | lane];   // conflict-free
            acc += ((word >> lane) & 1ull) ? qv : 0.f;
        }
        acc = wave_reduce_sum(acc);
        if (lane == 0) s_lds[m] = acc;
    }
    __syncthreads();

    // ---- phase 2: chunk softmax stats ----
    if (wave == 0) {
        float s = (lane < CM) ? s_lds[lane] : -3.0e38f;
        float mx = s;
        #pragma unroll
        for (int off = 16; off > 0; off >>= 1) mx = fmaxf(mx, __shfl_xor(mx, off, 64));
        float p = (lane < CM) ? expf(s - mx) : 0.f;
        float z = p;
        #pragma unroll
        for (int off = 16; off > 0; off >>= 1) z += __shfl_xor(z, off, 64);
        if (lane < CM) p_lds[lane] = p;
        if (lane == 0) { mu_g[blockIdx.x] = mx; z_g[blockIdx.x] = z; }
    }
    __syncthreads();

    // ---- phase 3: weighted bit-sum; thread t -> e0 = t, e1 = t + 512 ----
    int w0  = ((t >> 8) << 2) | (t & 3);
    int bit = (t >> 2) & 63;
    float a0 = 0.f, a1 = 0.f;
    #pragma unroll 8
    for (int m = 0; m < CM; ++m) {
        float p  = p_lds[m];
        u64   lo = pk[m * 16 + w0];
        u64   hi = pk[m * 16 + w0 + 8];
        a0 += ((lo >> bit) & 1ull) ? p : 0.f;
        a1 += ((hi >> bit) & 1ull) ? p : 0.f;
    }
    float* par = pa + (size_t)blockIdx.x * ED;
    par[t]       = a0;
    par[t + 512] = a1;
}

// K3: combine + GEMV. Block per (n, v-tile of 32). Wave 0 builds
// coef[c] = exp(mu_c - mu)/Z, 1024 threads combine pa into a_lds,
// then 16 waves x 2 v each dot with Wb_w.
__global__ __launch_bounds__(1024) void k_out(const float* __restrict__ pa,
                                              const float* __restrict__ mu_g,
                                              const float* __restrict__ z_g,
                                              const float* __restrict__ Wb_w,
                                              const float* __restrict__ Wb_b,
                                              float* __restrict__ out) {
    int n  = blockIdx.x >> 4;
    int vt = blockIdx.x & 15;
    int t  = threadIdx.x;
    int wave = t >> 6, lane = t & 63;
    __shared__ float coef[CH];
    __shared__ float a_lds[ED];

    if (wave == 0) {
        float m_c = mu_g[n * CH + lane];
        float mx = m_c;
        #pragma unroll
        for (int off = 32; off > 0; off >>= 1) mx = fmaxf(mx, __shfl_xor(mx, off, 64));
        float cf = expf(m_c - mx);
        float zc = z_g[n * CH + lane] * cf;
        float Z = zc;
        #pragma unroll
        for (int off = 32; off > 0; off >>= 1) Z += __shfl_xor(Z, off, 64);
        coef[lane] = cf / Z;
    }
    __syncthreads();

    float acc = 0.f;
    #pragma unroll
    for (int ci = 0; ci < CH; ++ci)
        acc += coef[ci] * pa[((size_t)(n * CH + ci)) * ED + t];
    a_lds[t] = acc;
    __syncthreads();

    #pragma unroll
    for (int i = 0; i < 2; ++i) {
        int v = vt * 32 + wave * 2 + i;
        const float* wr = Wb_w + (size_t)v * ED;
        float d = 0.f;
        #pragma unroll
        for (int k = 0; k < ED; k += 256) {
            int idx = k + lane * 4;
            float4 wv = *reinterpret_cast<const float4*>(wr + idx);
            float4 av = *reinterpret_cast<const float4*>(&a_lds[idx]);
            d += av.x * wv.x + av.y * wv.y + av.z * wv.z + av.w * wv.w;
        }
        d = wave_reduce_sum(d);
        if (lane == 0) out[n * VD + v] = d + Wb_b[v];
    }
}

extern "C" void kernel_launch(void* const* d_in, const int* in_sizes, int n_in,
                              void* d_out, int out_size, void* d_ws, size_t ws_size,
                              hipStream_t stream) {
    const int*   tokens = (const int*)  d_in[0];
    const float* Wa_w   = (const float*)d_in[1];
    const float* Wa_b   = (const float*)d_in[2];
    const float* Wb_w   = (const float*)d_in[3];
    const float* Wb_b   = (const float*)d_in[4];
    float* out = (float*)d_out;

    u64*   pk_g  = (u64*)d_ws;                           // 8*2048*16 u64 = 2 MB
    float* q_row = (float*)(pk_g + (size_t)NB * LS * 16);// 8192
    float* pa    = q_row + NB * ED;                      // 8*64*1024 = 524288
    float* mu_g  = pa + (size_t)NB * CH * ED;            // 512
    float* z_g   = mu_g + NB * CH;                       // 512

    // 1) pack (blocks 0..1023) + qrow (blocks 1024..3071): the only 64 MB pass
    k_pack_qrow<<<dim3(3072), dim3(256), 0, stream>>>(tokens, Wa_w, Wa_b, q_row, pk_g);
    // 2) flash from packed bits: 512 blocks of 512 (2 MB, L2-hot)
    k_flash<<<dim3(NB * CH), dim3(512), 0, stream>>>(q_row, pk_g, pa, mu_g, z_g);
    // 3) combine + output GEMV: 128 blocks of 1024
    k_out<<<dim3(NB * 16), dim3(1024), 0, stream>>>(pa, mu_g, z_g, Wb_w, Wb_b, out);
}